// Round 8
// baseline (429.187 us; speedup 1.0000x reference)
//
#include <hip/hip_runtime.h>
#include <math.h>

#define D_MODEL 512
#define HEAD_DIM 64
#define NUM_HEADS 8
#define SEQ 2048
#define BATCH 4
#define ROWS (BATCH * SEQ)  // 8192
#define PLANE ((size_t)ROWS * D_MODEL)  // 4194304 elems
#define NT (SEQ / 64)
#define WSZ (D_MODEL * D_MODEL)  // 262144

typedef short v8s __attribute__((ext_vector_type(8)));
typedef float v4f __attribute__((ext_vector_type(4)));

#define MFMA16(a, b, c) __builtin_amdgcn_mfma_f32_16x16x32_bf16(a, b, c, 0, 0, 0)

__device__ __forceinline__ unsigned short bf16_rne(float x) {
  unsigned u = __float_as_uint(x);
  u += 0x7fffu + ((u >> 16) & 1u);
  return (unsigned short)(u >> 16);
}
__device__ __forceinline__ float bf16f(unsigned short h) {
  return __uint_as_float(((unsigned)h) << 16);
}

// ---------------------------------------------------------------------------
// W prep: convert Wq/Wk/Wv fp32 -> bf16 hi/lo planes ONCE (r6 wasted ~320
// VALU/thread/iter re-converting W per row-block; W is reused 128x).
// Planes live in the vt region (dead until vtrans runs, which is after proj).
// ---------------------------------------------------------------------------
__global__ __launch_bounds__(256) void wprep_kernel(
    const float* __restrict__ Wq, const float* __restrict__ Wk,
    const float* __restrict__ Wv, unsigned short* __restrict__ wh,
    unsigned short* __restrict__ wl) {
  const int z = blockIdx.z;
  const float* W = (z == 0) ? Wq : (z == 1) ? Wk : Wv;
  const size_t base = (size_t)z * WSZ;
  const size_t idx = ((size_t)blockIdx.x * 256 + threadIdx.x) * 8;
  float xv[8];
  *reinterpret_cast<float4*>(&xv[0]) =
      *reinterpret_cast<const float4*>(&W[idx]);
  *reinterpret_cast<float4*>(&xv[4]) =
      *reinterpret_cast<const float4*>(&W[idx + 4]);
  unsigned short h8[8], l8[8];
#pragma unroll
  for (int j = 0; j < 8; ++j) {
    h8[j] = bf16_rne(xv[j]);
    l8[j] = bf16_rne(xv[j] - bf16f(h8[j]));
  }
  *reinterpret_cast<uint4*>(&wh[base + idx]) = *reinterpret_cast<uint4*>(&h8[0]);
  *reinterpret_cast<uint4*>(&wl[base + idx]) = *reinterpret_cast<uint4*>(&l8[0]);
}

// ---------------------------------------------------------------------------
// MFMA projection: y = x @ W^T + b, 3-term bf16 hi/lo split. W now loaded
// pre-converted (wprep); only x converts in-kernel. z==0 pre-scaled 0.125.
// ---------------------------------------------------------------------------
__global__ __launch_bounds__(256) void proj_mfma_kernel(
    const float* __restrict__ q, const float* __restrict__ k,
    const float* __restrict__ v, const unsigned short* __restrict__ wh_all,
    const unsigned short* __restrict__ wl_all, const float* __restrict__ bq,
    const float* __restrict__ bk, const float* __restrict__ bv,
    unsigned short* __restrict__ q_hi, unsigned short* __restrict__ q_lo,
    unsigned short* __restrict__ k_hi, unsigned short* __restrict__ k_lo,
    unsigned short* __restrict__ v_b) {
  const int z = blockIdx.z;
  const float* x = (z == 0) ? q : (z == 1) ? k : v;
  const float* bias = (z == 0) ? bq : (z == 1) ? bk : bv;
  const unsigned short* whp = wh_all + (size_t)z * WSZ;
  const unsigned short* wlp = wl_all + (size_t)z * WSZ;

  __shared__ unsigned short Xh[64][40];
  __shared__ unsigned short Xl[64][40];
  __shared__ unsigned short Wh[256][40];
  __shared__ unsigned short Wl[256][40];

  const int tid = threadIdx.x;
  const int w = tid >> 6;
  const int lane = tid & 63;
  const int g = lane >> 4;
  const int c = lane & 15;
  const int m0 = blockIdx.x * 64;
  const int n0 = blockIdx.y * 256;

  v4f acc[16];
#pragma unroll
  for (int i = 0; i < 16; ++i) acc[i] = (v4f){0.f, 0.f, 0.f, 0.f};

  const int xr = tid >> 2;       // x staging row 0..63
  const int xs = (tid & 3) * 8;  // x k offset 0,8,16,24

  for (int k0 = 0; k0 < D_MODEL; k0 += 32) {
    // issue global loads before the barrier
    float xv[8];
    *reinterpret_cast<float4*>(&xv[0]) = *reinterpret_cast<const float4*>(
        &x[(size_t)(m0 + xr) * D_MODEL + k0 + xs]);
    *reinterpret_cast<float4*>(&xv[4]) = *reinterpret_cast<const float4*>(
        &x[(size_t)(m0 + xr) * D_MODEL + k0 + xs + 4]);
    uint4 wh4[4], wl4[4];
#pragma unroll
    for (int i = 0; i < 4; ++i) {
      const size_t wa = (size_t)(n0 + tid) * D_MODEL + k0 + i * 8;
      wh4[i] = *reinterpret_cast<const uint4*>(&whp[wa]);
      wl4[i] = *reinterpret_cast<const uint4*>(&wlp[wa]);
    }
    __syncthreads();
    {
      unsigned short h8[8], l8[8];
#pragma unroll
      for (int j = 0; j < 8; ++j) {
        h8[j] = bf16_rne(xv[j]);
        l8[j] = bf16_rne(xv[j] - bf16f(h8[j]));
      }
      *reinterpret_cast<uint4*>(&Xh[xr][xs]) = *reinterpret_cast<uint4*>(&h8[0]);
      *reinterpret_cast<uint4*>(&Xl[xr][xs]) = *reinterpret_cast<uint4*>(&l8[0]);
#pragma unroll
      for (int i = 0; i < 4; ++i) {
        *reinterpret_cast<uint4*>(&Wh[tid][i * 8]) = wh4[i];
        *reinterpret_cast<uint4*>(&Wl[tid][i * 8]) = wl4[i];
      }
    }
    __syncthreads();

    const v8s ah = *reinterpret_cast<const v8s*>(&Xh[w * 16 + c][g * 8]);
    const v8s al = *reinterpret_cast<const v8s*>(&Xl[w * 16 + c][g * 8]);
#pragma unroll
    for (int nt = 0; nt < 16; ++nt) {
      const v8s bh = *reinterpret_cast<const v8s*>(&Wh[nt * 16 + c][g * 8]);
      const v8s bl = *reinterpret_cast<const v8s*>(&Wl[nt * 16 + c][g * 8]);
      acc[nt] = MFMA16(ah, bh, acc[nt]);
      acc[nt] = MFMA16(ah, bl, acc[nt]);
      acc[nt] = MFMA16(al, bh, acc[nt]);
    }
  }

  if (z < 2) {
    unsigned short* hp = (z == 0) ? q_hi : k_hi;
    unsigned short* lp = (z == 0) ? q_lo : k_lo;
    const float sc = (z == 0) ? 0.125f : 1.0f;
#pragma unroll
    for (int nt = 0; nt < 16; ++nt) {
      const float bb = bias[n0 + nt * 16 + c];
#pragma unroll
      for (int r = 0; r < 4; ++r) {
        const float y = (acc[nt][r] + bb) * sc;
        const unsigned short hb = bf16_rne(y);
        const unsigned short lb = bf16_rne(y - bf16f(hb));
        const size_t off =
            (size_t)(m0 + w * 16 + g * 4 + r) * D_MODEL + n0 + nt * 16 + c;
        hp[off] = hb;
        lp[off] = lb;
      }
    }
  } else {
#pragma unroll
    for (int nt = 0; nt < 16; ++nt) {
      const float bb = bias[n0 + nt * 16 + c];
#pragma unroll
      for (int r = 0; r < 4; ++r) {
        const size_t off =
            (size_t)(m0 + w * 16 + g * 4 + r) * D_MODEL + n0 + nt * 16 + c;
        v_b[off] = bf16_rne(acc[nt][r] + bb);
      }
    }
  }
}

// ---------------------------------------------------------------------------
// V transpose: v_b [b*2048+kpos][512] -> vt [b*512+col][2048] (bf16).
// NOTE: runs AFTER proj (vt region holds W planes until then).
// ---------------------------------------------------------------------------
__global__ __launch_bounds__(256) void vtrans_kernel(
    const unsigned short* __restrict__ vb, unsigned short* __restrict__ vt) {
  __shared__ unsigned short T[64][72];
  const int kt = blockIdx.x, ct = blockIdx.y, b = blockIdx.z;
  const int t = threadIdx.x;
  const int r = t >> 3, seg = t & 7;
#pragma unroll
  for (int i = 0; i < 2; ++i) {
    const int row = r + 32 * i;
    const uint4 val = *reinterpret_cast<const uint4*>(
        &vb[((size_t)(b * 2048 + kt * 64 + row)) * 512 + ct * 64 + seg * 8]);
    *reinterpret_cast<uint4*>(&T[row][seg * 8]) = val;
  }
  __syncthreads();
#pragma unroll
  for (int i = 0; i < 2; ++i) {
    const int col = r + 32 * i;
    unsigned short tmp[8];
#pragma unroll
    for (int j = 0; j < 8; ++j) tmp[j] = T[seg * 8 + j][col];
    *reinterpret_cast<uint4*>(
        &vt[((size_t)(b * 512 + ct * 64 + col)) * 2048 + kt * 64 + seg * 8]) =
        *reinterpret_cast<uint4*>(&tmp[0]);
  }
}

// ---------------------------------------------------------------------------
// Flash attention, bf16 MFMA, fp32-grade. Round-7 structure:
// - qt=1: 4 waves x 16 q-rows = 64 q-rows/block, grid 1024.
// - K/V LDS [64][64] u16 with granule-XOR swizzle gran' = gran ^ (row&7):
//   r6's pitch-72 aliased rows 8 apart (8-way quad conflicts on every b128
//   read); swizzled pattern is uniform 8 lanes/quad = b128 minimum.
// - Pl [4][16][64] u32 (pack-writes 4-way, acceptable) -> LDS total 40960 B
//   = EXACTLY 4 blocks/CU; qt=1 state ~105 VGPR fits (256,4)'s 128 cap.
//   Spill tripwire: WRITE_SIZE must stay ~16 MB (r4/r5 lesson).
// - T14 prefetch kept (proven in r6: WRITE clean, -24us).
// ---------------------------------------------------------------------------
__global__ __launch_bounds__(256, 4) void mha_attn_mfma(
    const unsigned short* __restrict__ qhi, const unsigned short* __restrict__ qlo,
    const unsigned short* __restrict__ khi, const unsigned short* __restrict__ klo,
    const unsigned short* __restrict__ vt, float* __restrict__ out) {
  __shared__ unsigned short Khs[64][64];
  __shared__ unsigned short Kls[64][64];
  __shared__ unsigned short Vts[64][64];
  __shared__ unsigned Pl[4][16][64];  // per-wave packed P (hi|lo<<16), swizzled

  const int tid = threadIdx.x;
  const int w = tid >> 6;
  const int lane = tid & 63;
  const int g = lane >> 4;
  const int c = lane & 15;
  const int bid = blockIdx.x;
  const int qt = bid & 31;       // 64-row q-tile
  const int h = (bid >> 5) & 7;  // head
  const int b = bid >> 8;        // batch
  const int q0 = qt * 64 + w * 16;

  // Q fragments (hi/lo), pre-scaled by 1/8 at projection.
  v8s qfh[2], qfl[2];
#pragma unroll
  for (int kh = 0; kh < 2; ++kh) {
    const size_t off =
        ((size_t)(b * 2048 + q0 + c)) * 512 + h * 64 + kh * 32 + g * 8;
    qfh[kh] = *reinterpret_cast<const v8s*>(&qhi[off]);
    qfl[kh] = *reinterpret_cast<const v8s*>(&qlo[off]);
  }

  v4f ctx[4];
#pragma unroll
  for (int dt = 0; dt < 4; ++dt) ctx[dt] = (v4f){0.f, 0.f, 0.f, 0.f};
  float mrun[4], lrun[4];
#pragma unroll
  for (int r = 0; r < 4; ++r) {
    mrun[r] = -1.0e30f;
    lrun[r] = 0.f;
  }

  const int srow = tid >> 3;  // 0..31
  const int sseg = tid & 7;   // 0..7
  const int sw0 = (sseg ^ (srow & 7)) * 8;  // swizzled granule (same for +32)

  uint4 sk0, sk1, sl0, sl1, sv0, sv1;
#define LOAD_TILE(KT)                                                          \
  {                                                                            \
    const size_t ka0 =                                                         \
        ((size_t)(b * 2048 + (KT) * 64 + srow)) * 512 + h * 64 + sseg * 8;     \
    const size_t ka1 = ka0 + (size_t)32 * 512;                                 \
    sk0 = *reinterpret_cast<const uint4*>(&khi[ka0]);                          \
    sk1 = *reinterpret_cast<const uint4*>(&khi[ka1]);                          \
    sl0 = *reinterpret_cast<const uint4*>(&klo[ka0]);                          \
    sl1 = *reinterpret_cast<const uint4*>(&klo[ka1]);                          \
    const size_t va0 =                                                         \
        ((size_t)(b * 512 + h * 64 + srow)) * 2048 + (KT) * 64 + sseg * 8;     \
    const size_t va1 = va0 + (size_t)32 * 2048;                                \
    sv0 = *reinterpret_cast<const uint4*>(&vt[va0]);                           \
    sv1 = *reinterpret_cast<const uint4*>(&vt[va1]);                           \
  }

  LOAD_TILE(0);  // prologue prefetch

  for (int kt = 0; kt < NT; ++kt) {
    __syncthreads();  // previous tile's LDS reads complete
    *reinterpret_cast<uint4*>(&Khs[srow][sw0]) = sk0;
    *reinterpret_cast<uint4*>(&Khs[srow + 32][sw0]) = sk1;
    *reinterpret_cast<uint4*>(&Kls[srow][sw0]) = sl0;
    *reinterpret_cast<uint4*>(&Kls[srow + 32][sw0]) = sl1;
    *reinterpret_cast<uint4*>(&Vts[srow][sw0]) = sv0;
    *reinterpret_cast<uint4*>(&Vts[srow + 32][sw0]) = sv1;
    __syncthreads();

    // issue NEXT tile's loads now: latency hides under compute (T14)
    const int ktn = (kt < NT - 1) ? kt + 1 : kt;
    LOAD_TILE(ktn);

    // ---- QK^T: 3-term split, 24 MFMAs ----
    v4f s[4];
#pragma unroll
    for (int ct = 0; ct < 4; ++ct) s[ct] = (v4f){0.f, 0.f, 0.f, 0.f};
#pragma unroll
    for (int kh = 0; kh < 2; ++kh) {
      const int gq = ((kh * 4 + g) ^ (c & 7)) * 8;  // swizzled read granule
#pragma unroll
      for (int ct = 0; ct < 4; ++ct) {
        const v8s bh = *reinterpret_cast<const v8s*>(&Khs[ct * 16 + c][gq]);
        const v8s bl = *reinterpret_cast<const v8s*>(&Kls[ct * 16 + c][gq]);
        s[ct] = MFMA16(qfh[kh], bh, s[ct]);
        s[ct] = MFMA16(qfh[kh], bl, s[ct]);
        s[ct] = MFMA16(qfl[kh], bh, s[ct]);
      }
    }

    // ---- online softmax (rows r = g*4+r across 16 c-lanes) ----
    float al[4];
#pragma unroll
    for (int r = 0; r < 4; ++r) {
      float mx = fmaxf(fmaxf(s[0][r], s[1][r]), fmaxf(s[2][r], s[3][r]));
      mx = fmaxf(mx, __shfl_xor(mx, 1, 16));
      mx = fmaxf(mx, __shfl_xor(mx, 2, 16));
      mx = fmaxf(mx, __shfl_xor(mx, 4, 16));
      mx = fmaxf(mx, __shfl_xor(mx, 8, 16));
      const float mn = fmaxf(mrun[r], mx);
      al[r] = __expf(mrun[r] - mn);
      mrun[r] = mn;
    }
#pragma unroll
    for (int ct = 0; ct < 4; ++ct)
#pragma unroll
      for (int r = 0; r < 4; ++r) s[ct][r] = __expf(s[ct][r] - mrun[r]);
#pragma unroll
    for (int r = 0; r < 4; ++r) {
      float ps = s[0][r] + s[1][r] + s[2][r] + s[3][r];
      ps += __shfl_xor(ps, 1, 16);
      ps += __shfl_xor(ps, 2, 16);
      ps += __shfl_xor(ps, 4, 16);
      ps += __shfl_xor(ps, 8, 16);
      lrun[r] = lrun[r] * al[r] + ps;
    }
#pragma unroll
    for (int dt = 0; dt < 4; ++dt)
#pragma unroll
      for (int r = 0; r < 4; ++r) ctx[dt][r] *= al[r];

    // ---- pack P hi|lo into swizzled u32 plane (s dies here) ----
#pragma unroll
    for (int ct = 0; ct < 4; ++ct)
#pragma unroll
      for (int r = 0; r < 4; ++r) {
        const float p = s[ct][r];
        const unsigned u = __float_as_uint(p);
        const unsigned hi = u >> 16;
        const float lof = p - __uint_as_float(u & 0xffff0000u);
        const unsigned lo = __float_as_uint(lof) >> 16;
        Pl[w][g * 4 + r][(ct * 16 + c) ^ (g << 2)] = hi | (lo << 16);
      }

    // ---- PV: single pass, hi+lo MFMAs (same-wave DS RAW, no barrier) ----
    const int cc4 = (c >> 2) << 2;
#pragma unroll
    for (int kh = 0; kh < 2; ++kh) {
      const uint4 a0 = *reinterpret_cast<const uint4*>(
          &Pl[w][c][(kh * 32 + g * 8) ^ cc4]);
      const uint4 a1 = *reinterpret_cast<const uint4*>(
          &Pl[w][c][(kh * 32 + g * 8 + 4) ^ cc4]);
      uint4 hh, ll;
      hh.x = (a0.x & 0xffffu) | (a0.y << 16);
      hh.y = (a0.z & 0xffffu) | (a0.w << 16);
      hh.z = (a1.x & 0xffffu) | (a1.y << 16);
      hh.w = (a1.z & 0xffffu) | (a1.w << 16);
      ll.x = (a0.x >> 16) | (a0.y & 0xffff0000u);
      ll.y = (a0.z >> 16) | (a0.w & 0xffff0000u);
      ll.z = (a1.x >> 16) | (a1.y & 0xffff0000u);
      ll.w = (a1.z >> 16) | (a1.w & 0xffff0000u);
      const v8s pah = __builtin_bit_cast(v8s, hh);
      const v8s pal = __builtin_bit_cast(v8s, ll);
      const int gq = ((kh * 4 + g) ^ (c & 7)) * 8;
#pragma unroll
      for (int dt = 0; dt < 4; ++dt) {
        const v8s vb = *reinterpret_cast<const v8s*>(&Vts[dt * 16 + c][gq]);
        ctx[dt] = MFMA16(pah, vb, ctx[dt]);
        ctx[dt] = MFMA16(pal, vb, ctx[dt]);
      }
    }
  }

  // ---- epilogue: normalize and store fp32 ----
  float inv[4];
#pragma unroll
  for (int r = 0; r < 4; ++r) inv[r] = 1.0f / lrun[r];
#pragma unroll
  for (int dt = 0; dt < 4; ++dt)
#pragma unroll
    for (int r = 0; r < 4; ++r)
      out[((size_t)(b * 2048 + q0 + g * 4 + r)) * 512 + h * 64 + dt * 16 + c] =
          ctx[dt][r] * inv[r];
}

extern "C" void kernel_launch(void* const* d_in, const int* in_sizes, int n_in,
                              void* d_out, int out_size, void* d_ws,
                              size_t ws_size, hipStream_t stream) {
  const float* q = (const float*)d_in[0];
  const float* k = (const float*)d_in[1];
  const float* v = (const float*)d_in[2];
  const float* Wq_w = (const float*)d_in[3];
  const float* Wq_b = (const float*)d_in[4];
  const float* Wk_w = (const float*)d_in[5];
  const float* Wk_b = (const float*)d_in[6];
  const float* Wv_w = (const float*)d_in[7];
  const float* Wv_b = (const float*)d_in[8];
  float* out = (float*)d_out;

  unsigned short* q_hi = (unsigned short*)d_ws;
  unsigned short* q_lo = q_hi + PLANE;
  unsigned short* k_hi = q_lo + PLANE;
  unsigned short* k_lo = k_hi + PLANE;
  unsigned short* v_b = k_lo + PLANE;
  unsigned short* vt = v_b + PLANE;  // 6 planes * 8 MiB = 48 MiB total
  // W bf16 planes alias the vt region (dead until vtrans, which runs after
  // proj has consumed them): 3*256K hi + 3*256K lo = 3 MiB < 8 MiB.
  unsigned short* w_hi = vt;
  unsigned short* w_lo = vt + (size_t)3 * WSZ;

  wprep_kernel<<<dim3(WSZ / (256 * 8), 1, 3), 256, 0, stream>>>(
      Wq_w, Wk_w, Wv_w, w_hi, w_lo);

  dim3 pgrid(ROWS / 64, D_MODEL / 256, 3);
  proj_mfma_kernel<<<pgrid, 256, 0, stream>>>(q, k, v, w_hi, w_lo, Wq_b, Wk_b,
                                              Wv_b, q_hi, q_lo, k_hi, k_lo,
                                              v_b);

  dim3 tgrid(SEQ / 64, D_MODEL / 64, BATCH);
  vtrans_kernel<<<tgrid, 256, 0, stream>>>(v_b, vt);

  dim3 agrid(BATCH * NUM_HEADS * (SEQ / 64));
  mha_attn_mfma<<<agrid, 256, 0, stream>>>(q_hi, q_lo, k_hi, k_lo, vt, out);
}